// Round 10
// baseline (249.173 us; speedup 1.0000x reference)
//
#include <hip/hip_runtime.h>

// Problem constants (B=1)
#define L_SEQ 4096
#define C_DIM 1024
#define H_NUM 16
#define D_HEAD 64
#define LDQK 2048

typedef __bf16 bf16x8 __attribute__((ext_vector_type(8)));
typedef __bf16 bf16x4 __attribute__((ext_vector_type(4)));
typedef float f32x4 __attribute__((ext_vector_type(4)));
typedef float f32x16 __attribute__((ext_vector_type(16)));
typedef unsigned int u32;
typedef u32 u32x4 __attribute__((ext_vector_type(4)));

#define AS1 __attribute__((address_space(1)))
#define AS3 __attribute__((address_space(3)))

#define SC_LOG2E 0.1803368801111204f  // 0.125 * log2(e)

__device__ inline __bf16 f2bf(float f) {
  unsigned u = __builtin_bit_cast(unsigned, f);
  u = (u + 0x7fffu + ((u >> 16) & 1u)) >> 16;
  unsigned short s = (unsigned short)u;
  return __builtin_bit_cast(__bf16, s);
}

__device__ inline void gload_lds16(const __bf16* g, __bf16* l) {
  __builtin_amdgcn_global_load_lds((const AS1 void*)g, (AS3 void*)l, 16, 0, 0);
}

// ------------- prep: x fp32->bf16 (blocks 0..4095) + 4x W^T cvt (4096..8191) --
__global__ __launch_bounds__(256) void prep(const float* __restrict__ x,
                                            const float* __restrict__ W0,
                                            const float* __restrict__ W1,
                                            const float* __restrict__ W2,
                                            const float* __restrict__ W3,
                                            __bf16* __restrict__ xb,
                                            __bf16* __restrict__ Wt) {
  __shared__ float t[32][33];
  int id = blockIdx.x;
  if (id < 4096) {
    int i = (id * 256 + threadIdx.x) * 4;
    float4 v = *(const float4*)(x + i);
    bf16x4 o = {f2bf(v.x), f2bf(v.y), f2bf(v.z), f2bf(v.w)};
    *(bf16x4*)(xb + i) = o;
    return;
  }
  id -= 4096;
  const int z = id >> 10;
  const int rem = id & 1023;
  const float* W = (z == 0) ? W0 : (z == 1) ? W1 : (z == 2) ? W2 : W3;
  __bf16* dst = Wt + (size_t)z * 1048576;
  const int tx = threadIdx.x & 31, ty = threadIdx.x >> 5;
  const int c0 = (rem & 31) * 32, r0 = (rem >> 5) * 32;
#pragma unroll
  for (int k = 0; k < 4; ++k)
    t[ty + k * 8][tx] = W[(size_t)(r0 + ty + k * 8) * C_DIM + c0 + tx];
  __syncthreads();
#pragma unroll
  for (int k = 0; k < 4; ++k)
    dst[(size_t)(c0 + ty + k * 8) * C_DIM + r0 + tx] = f2bf(t[tx][ty + k * 8]);
}

// ============ shared GEMM tile body: 128x128, BK=64, XOR-swizzled LDS ========
// As/Bs rows are 128B (64 bf16); 16B chunks XOR-swizzled by (row&7) -> all
// fragment ds_read_b128 conflict-free (vs 8-way in the BK=32 linear layout).
template <bool OUT_BF16>
__device__ __forceinline__ void gemm_body(const __bf16* A, const __bf16* Bt,
                                          void* Cp, int N, int K,
                                          size_t arow0, size_t brow0, float esc,
                                          __bf16* As, __bf16* Bs) {
  const int tid = threadIdx.x;
  const int lane = tid & 63;
  const int wave = tid >> 6;
  const int wm = wave >> 1, wn = wave & 1;
  const int c16 = lane & 15, g4 = lane >> 4;
  const int rl = lane >> 3;              // 0..7 row-in-group
  const int cs = (lane & 7) ^ rl;        // pre-swizzled source chunk

  f32x4 acc[4][4] = {};
  char* const AsB = (char*)As;
  char* const BsB = (char*)Bs;

  for (int kt = 0; kt < K; kt += 64) {
#pragma unroll
    for (int i = 0; i < 4; ++i) {
      const int row0 = i * 32 + wave * 8;
      gload_lds16(A + (arow0 + row0 + rl) * K + kt + cs * 8, As + row0 * 64);
      gload_lds16(Bt + (brow0 + row0 + rl) * K + kt + cs * 8, Bs + row0 * 64);
    }
    __syncthreads();
#pragma unroll
    for (int kh = 0; kh < 2; ++kh) {
      bf16x8 af[4], bfr[4];
#pragma unroll
      for (int mi = 0; mi < 4; ++mi) {
        const int row = wm * 64 + mi * 16 + c16;
        af[mi] = *(const bf16x8*)(AsB + row * 128 + (((kh * 4 + g4) ^ (row & 7)) << 4));
      }
#pragma unroll
      for (int ni = 0; ni < 4; ++ni) {
        const int row = wn * 64 + ni * 16 + c16;
        bfr[ni] = *(const bf16x8*)(BsB + row * 128 + (((kh * 4 + g4) ^ (row & 7)) << 4));
      }
#pragma unroll
      for (int mi = 0; mi < 4; ++mi)
#pragma unroll
        for (int ni = 0; ni < 4; ++ni)
          acc[mi][ni] = __builtin_amdgcn_mfma_f32_16x16x32_bf16(af[mi], bfr[ni], acc[mi][ni], 0, 0, 0);
    }
    __syncthreads();
  }

#pragma unroll
  for (int mi = 0; mi < 4; ++mi)
#pragma unroll
    for (int ni = 0; ni < 4; ++ni)
#pragma unroll
      for (int i = 0; i < 4; ++i) {
        size_t row = arow0 + wm * 64 + mi * 16 + g4 * 4 + i;
        size_t col = brow0 + wn * 64 + ni * 16 + c16;
        if (OUT_BF16)
          ((__bf16*)Cp)[row * N + col] = f2bf(acc[mi][ni][i] * esc);
        else
          ((float*)Cp)[row * N + col] = acc[mi][ni][i];
      }
}

// ---- fused QK-projection + V^T-projection (independent jobs, one launch) ----
__global__ __launch_bounds__(256) void gemm_qkv(const __bf16* __restrict__ xb,
                                                const __bf16* __restrict__ WqkT,
                                                const __bf16* __restrict__ WvT,
                                                __bf16* __restrict__ QKb,
                                                __bf16* __restrict__ Vtb) {
  __shared__ __bf16 As[128 * 64];
  __shared__ __bf16 Bs[128 * 64];
  int g = blockIdx.x;
  if (g < 512) {
    size_t arow0 = (size_t)(g & 31) * 128;
    size_t brow0 = (size_t)(g >> 5) * 128;
    float esc = ((int)brow0 < 1024) ? SC_LOG2E : 1.0f;
    gemm_body<true>(xb, WqkT, QKb, 2048, 1024, arow0, brow0, esc, As, Bs);
  } else {
    g -= 512;
    size_t arow0 = (size_t)(g & 7) * 128;
    size_t brow0 = (size_t)(g >> 3) * 128;
    gemm_body<true>(WvT, xb, Vtb, 4096, 1024, arow0, brow0, 1.0f, As, Bs);
  }
}

// ---------------- output GEMM: out(4096x1024 f32) = Ab @ WoT^T ---------------
__global__ __launch_bounds__(256) void gemm_out(const __bf16* __restrict__ A,
                                                const __bf16* __restrict__ Bt,
                                                float* __restrict__ Cp) {
  __shared__ __bf16 As[128 * 64];
  __shared__ __bf16 Bs[128 * 64];
  size_t arow0 = (size_t)(blockIdx.x) * 128;
  size_t brow0 = (size_t)(blockIdx.y) * 128;
  gemm_body<false>(A, Bt, Cp, 1024, 1024, arow0, brow0, 1.0f, As, Bs);
}

// ---------------- causal flash attention, 32x32 swapped-QK^T ------------------
// grid 512 x 256 threads (3 blocks/CU): 32 q-tiles of 128 rows x 16 heads.
// 4 waves x 32 q rows; lane holds full P row in regs (T12). 3-deep KV LDS
// buffer, ONE barrier/iter {stage(n+1); vmcnt(4); barrier; compute(n)}.
// Defer-max (T13): skip rescale while max grows <= 8 (exp2 domain).
// Epilogue reuses Ks as transpose buffer (post-loop barrier).
__global__ __launch_bounds__(256, 3) void attn_fwd(const __bf16* __restrict__ Q,
                                                   const __bf16* __restrict__ Kg,
                                                   const __bf16* __restrict__ Vt,
                                                   __bf16* __restrict__ O) {
  const int bid = blockIdx.x;
  const int h = bid & 15;
  const int g = (bid >> 4) & 15;
  const int qt = (bid < 256) ? (31 - g) : g;
  const int nt = 2 * qt + 2;

  __shared__ __bf16 Ks[3][64 * 64];  // [key][d], XOR-swizzled (24KB)
  __shared__ __bf16 Vs[3][64 * 64];  // [d][key], XOR-swizzled (24KB)

  const int tid = threadIdx.x;
  const int lane = tid & 63;
  const int wave = tid >> 6;
  const int l31 = lane & 31;
  const int hl = lane >> 5;
  const int qbase = qt * 128 + wave * 32;
  const int q = qbase + l31;             // this lane's q row
  const int kvmax_w = (qbase + 31) >> 6; // last KV tile this warp computes

  const int rl = lane >> 3;
  const int cs = (lane & 7) ^ rl;  // pre-swizzled source chunk

  auto stage = [&](int kv, int b) {
#pragma unroll
    for (int i = 0; i < 2; ++i) {
      const int r = (i * 4 + wave) * 8 + rl;
      gload_lds16(Kg + (size_t)(kv * 64 + r) * LDQK + h * D_HEAD + cs * 8,
                  &Ks[b][(i * 4 + wave) * 512]);
      gload_lds16(Vt + (size_t)(h * D_HEAD + r) * L_SEQ + kv * 64 + cs * 8,
                  &Vs[b][(i * 4 + wave) * 512]);
    }
  };

  // Q B-fragments first (VMEM-counted; drained by the first vmcnt(4))
  bf16x8 qf[4];
  {
    const __bf16* qp = Q + (size_t)q * LDQK + h * D_HEAD + hl * 8;
#pragma unroll
    for (int s = 0; s < 4; ++s) qf[s] = *(const bf16x8*)(qp + s * 16);
  }

  stage(0, 0);

  f32x16 acc0 = {}, acc1 = {};  // O^T[d][q], d-tiles 0/1
  float m = -1e30f, lsum = 0.f;

  int bc = 0;  // compute buffer = kv % 3
  for (int kv = 0; kv < nt; ++kv) {
    if (kv + 1 < nt) {
      int bs = bc + 1; if (bs == 3) bs = 0;
      stage(kv + 1, bs);
      asm volatile("s_waitcnt vmcnt(4)" ::: "memory");
    } else {
      asm volatile("s_waitcnt vmcnt(0)" ::: "memory");
    }
    __builtin_amdgcn_sched_barrier(0);
    __builtin_amdgcn_s_barrier();
    __builtin_amdgcn_sched_barrier(0);

    if (kv <= kvmax_w) {
      char* const KsB = (char*)&Ks[bc][0];
      char* const VsB = (char*)&Vs[bc][0];

      // S^T = K . Q^T : lane holds q=l31, key rows kr(reg)+{0,32}
      f32x16 st0 = {}, st1 = {};
      __builtin_amdgcn_s_setprio(1);
#pragma unroll
      for (int s = 0; s < 4; ++s) {
        const int ch = s * 2 + hl;
        bf16x8 a0 = *(const bf16x8*)(KsB + l31 * 128 + ((ch ^ (l31 & 7)) << 4));
        bf16x8 a1 = *(const bf16x8*)(KsB + (32 + l31) * 128 + ((ch ^ (l31 & 7)) << 4));
        st0 = __builtin_amdgcn_mfma_f32_32x32x16_bf16(a0, qf[s], st0, 0, 0, 0);
        st1 = __builtin_amdgcn_mfma_f32_32x32x16_bf16(a1, qf[s], st1, 0, 0, 0);
      }
      __builtin_amdgcn_s_setprio(0);

      // causal mask: only the (always-partial) last tile of this warp
      if (kv == kvmax_w) {
#pragma unroll
        for (int r = 0; r < 16; ++r) {
          const int kr = (r & 3) + 8 * (r >> 2) + 4 * hl;
          const int k0 = kv * 64 + kr;
          st0[r] = (k0 <= q) ? st0[r] : -1e30f;
          st1[r] = (k0 + 32 <= q) ? st1[r] : -1e30f;
        }
      }

      // row max: in-lane tree + one cross-half swap
      float t[16];
#pragma unroll
      for (int r = 0; r < 16; ++r) t[r] = fmaxf(st0[r], st1[r]);
#pragma unroll
      for (int w = 8; w > 0; w >>= 1)
#pragma unroll
        for (int r = 0; r < w; ++r) t[r] = fmaxf(t[r], t[r + w]);
      float mx = fmaxf(t[0], __shfl_xor(t[0], 32, 64));

      // defer-max: rescale only when the running max grows by > 8 (exp2 dom.)
      const bool noskip = !__all(mx <= m + 8.0f);
      float corr = 1.0f;
      if (noskip) {
        const float mnew = fmaxf(m, mx);
        corr = exp2f(m - mnew);
        m = mnew;
      }

      // exp2 + row sum
#pragma unroll
      for (int r = 0; r < 16; ++r) {
        st0[r] = exp2f(st0[r] - m);
        st1[r] = exp2f(st1[r] - m);
      }
      float sm[16];
#pragma unroll
      for (int r = 0; r < 16; ++r) sm[r] = st0[r] + st1[r];
#pragma unroll
      for (int w = 8; w > 0; w >>= 1)
#pragma unroll
        for (int r = 0; r < w; ++r) sm[r] = sm[r] + sm[r + w];
      float sl = sm[0] + __shfl_xor(sm[0], 32, 64);
      if (noskip) {
        lsum = lsum * corr + sl;
        acc0 *= corr;
        acc1 *= corr;
      } else {
        lsum += sl;
      }

      // P -> bf16 pk words (pairs of consecutive keys)
      u32 w0[8], w1[8];
#pragma unroll
      for (int i = 0; i < 8; ++i) {
        asm("v_cvt_pk_bf16_f32 %0, %1, %2" : "=v"(w0[i]) : "v"(st0[2 * i]), "v"(st0[2 * i + 1]));
        asm("v_cvt_pk_bf16_f32 %0, %1, %2" : "=v"(w1[i]) : "v"(st1[2 * i]), "v"(st1[2 * i + 1]));
      }
      // cross-half exchange: one shfl serves both directions
      u32 e0a = (u32)__shfl_xor((int)(hl ? w0[0] : w0[2]), 32, 64);
      u32 e0b = (u32)__shfl_xor((int)(hl ? w0[1] : w0[3]), 32, 64);
      u32 e0c = (u32)__shfl_xor((int)(hl ? w0[4] : w0[6]), 32, 64);
      u32 e0d = (u32)__shfl_xor((int)(hl ? w0[5] : w0[7]), 32, 64);
      u32 e1a = (u32)__shfl_xor((int)(hl ? w1[0] : w1[2]), 32, 64);
      u32 e1b = (u32)__shfl_xor((int)(hl ? w1[1] : w1[3]), 32, 64);
      u32 e1c = (u32)__shfl_xor((int)(hl ? w1[4] : w1[6]), 32, 64);
      u32 e1d = (u32)__shfl_xor((int)(hl ? w1[5] : w1[7]), 32, 64);
      u32x4 f0 = hl ? (u32x4){e0a, e0b, w0[2], w0[3]} : (u32x4){w0[0], w0[1], e0a, e0b};
      u32x4 f1 = hl ? (u32x4){e0c, e0d, w0[6], w0[7]} : (u32x4){w0[4], w0[5], e0c, e0d};
      u32x4 f2 = hl ? (u32x4){e1a, e1b, w1[2], w1[3]} : (u32x4){w1[0], w1[1], e1a, e1b};
      u32x4 f3 = hl ? (u32x4){e1c, e1d, w1[6], w1[7]} : (u32x4){w1[4], w1[5], e1c, e1d};
      bf16x8 pb0 = __builtin_bit_cast(bf16x8, f0);
      bf16x8 pb1 = __builtin_bit_cast(bf16x8, f1);
      bf16x8 pb2 = __builtin_bit_cast(bf16x8, f2);
      bf16x8 pb3 = __builtin_bit_cast(bf16x8, f3);

      // O^T += V^T . P^T
      __builtin_amdgcn_s_setprio(1);
#pragma unroll
      for (int s = 0; s < 4; ++s) {
        const bf16x8 pb = (s == 0) ? pb0 : (s == 1) ? pb1 : (s == 2) ? pb2 : pb3;
        const int ch = s * 2 + hl;
        bf16x8 va0 = *(const bf16x8*)(VsB + l31 * 128 + ((ch ^ (l31 & 7)) << 4));
        bf16x8 va1 = *(const bf16x8*)(VsB + (32 + l31) * 128 + ((ch ^ (l31 & 7)) << 4));
        acc0 = __builtin_amdgcn_mfma_f32_32x32x16_bf16(va0, pb, acc0, 0, 0, 0);
        acc1 = __builtin_amdgcn_mfma_f32_32x32x16_bf16(va1, pb, acc1, 0, 0, 0);
      }
      __builtin_amdgcn_s_setprio(0);
    }

    bc = bc + 1; if (bc == 3) bc = 0;
  }

  // all waves done reading Ks/Vs -> safe to reuse Ks as transpose buffer
  __builtin_amdgcn_sched_barrier(0);
  __builtin_amdgcn_s_barrier();
  __builtin_amdgcn_sched_barrier(0);

  // epilogue: normalize, transpose O^T->O via per-warp swizzled LDS, store
  const float rinv = 1.0f / lsum;
  char* const Po = (char*)&Ks[0][0] + wave * 4096;  // 32q x 64d bf16 = 4KB/warp
#pragma unroll
  for (int dt = 0; dt < 2; ++dt) {
#pragma unroll
    for (int i = 0; i < 8; ++i) {
      const int r = 2 * i;
      const int d = dt * 32 + (r & 3) + 8 * (r >> 2) + 4 * hl;
      float lo = (dt ? acc1[r] : acc0[r]) * rinv;
      float hi = (dt ? acc1[r + 1] : acc0[r + 1]) * rinv;
      u32 wv;
      asm("v_cvt_pk_bf16_f32 %0, %1, %2" : "=v"(wv) : "v"(lo), "v"(hi));
      *(u32*)(Po + l31 * 128 + (((d >> 3) ^ (l31 & 7)) << 4) + (d & 7) * 2) = wv;
    }
  }
  asm volatile("s_waitcnt lgkmcnt(0)" ::: "memory");
  __builtin_amdgcn_sched_barrier(0);
#pragma unroll
  for (int j = 0; j < 4; ++j) {
    const int qr = lane >> 1;
    const int c = (lane & 1) * 4 + j;
    bf16x8 ov = *(const bf16x8*)(Po + qr * 128 + ((c ^ (qr & 7)) << 4));
    *(bf16x8*)(O + (size_t)(qbase + qr) * C_DIM + h * D_HEAD + c * 8) = ov;
  }
}

extern "C" void kernel_launch(void* const* d_in, const int* in_sizes, int n_in,
                              void* d_out, int out_size, void* d_ws, size_t ws_size,
                              hipStream_t stream) {
  const float* x = (const float*)d_in[0];
  const float* Wq = (const float*)d_in[1];
  const float* Wk = (const float*)d_in[2];
  const float* Wv = (const float*)d_in[3];
  const float* Wo = (const float*)d_in[4];
  float* out = (float*)d_out;

  char* ws = (char*)d_ws;
  __bf16* xb    = (__bf16*)(ws);                 // [0,8M) x bf16; reused as Ab
  __bf16* WqkvT = (__bf16*)(ws + (8u << 20));    // [8M,16M) WqT,WkT,WvT,WoT
  __bf16* QKb   = (__bf16*)(ws + (16u << 20));   // [16M,32M) 4096x2048
  __bf16* Vtb   = (__bf16*)(ws + (32u << 20));   // [32M,40M) 1024x4096
  __bf16* WvT   = WqkvT + (size_t)2 * 1048576;
  __bf16* WoT   = WqkvT + (size_t)3 * 1048576;
  __bf16* Ab    = xb;

  prep<<<8192, 256, 0, stream>>>(x, Wq, Wk, Wv, Wo, xb, WqkvT);

  gemm_qkv<<<768, 256, 0, stream>>>(xb, WqkvT, WvT, QKb, Vtb);

  attn_fwd<<<512, 256, 0, stream>>>(QKb, QKb + 1024, Vtb, Ab);

  gemm_out<<<dim3(32, 8), 256, 0, stream>>>(Ab, WoT, out);
}